// Round 1
// baseline (282.174 us; speedup 1.0000x reference)
//
#include <hip/hip_runtime.h>

// out[b,l,d] = log( sum_e gates[b,e] * exp(xs[e,b,l,d]) ), eps if sum==0
// E=8, B=128, L=96, D=512. Pure memory-bound elementwise-with-reduction-over-E.

constexpr int E_ = 8;
constexpr int B_ = 128;
constexpr int L_ = 96;
constexpr int D_ = 512;
constexpr int LD_ = L_ * D_;                         // 49152
constexpr long long N_ = (long long)B_ * LD_;        // 6291456 elements per expert

__global__ __launch_bounds__(256) void moe_log_combine_kernel(
    const float* __restrict__ xs,      // [E, B, L, D]
    const float* __restrict__ gates,   // [B, E]
    float* __restrict__ out)           // [B, L, D]
{
    const long long nvec = N_ / 4;     // float4 elements of output
    long long v = (long long)blockIdx.x * blockDim.x + threadIdx.x;
    if (v >= nvec) return;

    const long long i = v * 4;                 // scalar element index
    const int b = (int)(i / LD_);              // batch index (wave-uniform mostly)

    // gates[b, 0..7] — two float4 loads (gates row is 32B-aligned since E=8)
    const float4 g0 = *reinterpret_cast<const float4*>(gates + (long long)b * E_);
    const float4 g1 = *reinterpret_cast<const float4*>(gates + (long long)b * E_ + 4);
    const float g[E_] = {g0.x, g0.y, g0.z, g0.w, g1.x, g1.y, g1.z, g1.w};

    float4 acc = make_float4(0.f, 0.f, 0.f, 0.f);

#pragma unroll
    for (int e = 0; e < E_; ++e) {
        const float4 x = *reinterpret_cast<const float4*>(xs + (long long)e * N_ + i);
        const float ge = g[e];
        acc.x = fmaf(ge, __expf(x.x), acc.x);
        acc.y = fmaf(ge, __expf(x.y), acc.y);
        acc.z = fmaf(ge, __expf(x.z), acc.z);
        acc.w = fmaf(ge, __expf(x.w), acc.w);
    }

    // reference: combined[combined==0] = float32(np.finfo(np.float64).eps)
    const float eps = 2.220446049250313e-16f;
    acc.x = (acc.x == 0.f) ? eps : acc.x;
    acc.y = (acc.y == 0.f) ? eps : acc.y;
    acc.z = (acc.z == 0.f) ? eps : acc.z;
    acc.w = (acc.w == 0.f) ? eps : acc.w;

    float4 r;
    r.x = __logf(acc.x);
    r.y = __logf(acc.y);
    r.z = __logf(acc.z);
    r.w = __logf(acc.w);

    *reinterpret_cast<float4*>(out + i) = r;
}

extern "C" void kernel_launch(void* const* d_in, const int* in_sizes, int n_in,
                              void* d_out, int out_size, void* d_ws, size_t ws_size,
                              hipStream_t stream) {
    const float* xs    = (const float*)d_in[0];   // [E,B,L,D] fp32
    const float* gates = (const float*)d_in[1];   // [B,E] fp32
    float* out = (float*)d_out;                   // [B,L,D] fp32

    const long long nvec = N_ / 4;                // 1,572,864 float4s
    const int block = 256;
    const int grid = (int)((nvec + block - 1) / block);  // 6144 blocks

    moe_log_combine_kernel<<<grid, block, 0, stream>>>(xs, gates, out);
}

// Round 3
// 280.890 us; speedup vs baseline: 1.0046x; 1.0046x over previous
//
#include <hip/hip_runtime.h>

// out[b,l,d] = log( sum_e gates[b,e] * exp(xs[e,b,l,d]) ), eps if sum==0
// E=8, B=128, L=96, D=512. Memory-bound; ~226 MB traffic/call.

typedef float f32x4 __attribute__((ext_vector_type(4)));

constexpr int E_   = 8;
constexpr int B_   = 128;
constexpr int LD_  = 96 * 512;        // 49152 scalars per (b) row
constexpr int N_   = B_ * LD_;        // 6291456 scalars per expert
constexpr int NV4  = N_ / 4;          // 1572864 float4s per expert
// Each block: 256 threads x 2 float4 = 512 float4s. LD_/4=12288 float4s per b
// -> 24 blocks per b -> b is block-uniform. Grid = NV4/512 = 3072 blocks.

__global__ __launch_bounds__(256) void moe_log_combine_kernel(
    const float* __restrict__ xs,      // [E, B, L, D]
    const float* __restrict__ gates,   // [B, E]
    float* __restrict__ out)           // [B, L, D]
{
    const f32x4* __restrict__ xs4  = reinterpret_cast<const f32x4*>(xs);
    f32x4* __restrict__       out4 = reinterpret_cast<f32x4*>(out);

    const int blk = blockIdx.x;               // 0..3071
    const int b   = blk / 24;                 // block-uniform batch index (SALU)

    // gates[b, 0..7] — block-uniform -> scalar loads
    float g[E_];
#pragma unroll
    for (int e = 0; e < E_; ++e) g[e] = gates[b * E_ + e];

    const int i0 = blk * 512 + (int)threadIdx.x;  // float4 index, 32-bit
    const int i1 = i0 + 256;

    f32x4 a0 = {0.f, 0.f, 0.f, 0.f};
    f32x4 a1 = {0.f, 0.f, 0.f, 0.f};

#pragma unroll
    for (int e = 0; e < E_; ++e) {
        const f32x4 x0 = xs4[e * NV4 + i0];
        const f32x4 x1 = xs4[e * NV4 + i1];
        const float ge = g[e];
#pragma unroll
        for (int j = 0; j < 4; ++j) {
            a0[j] = fmaf(ge, __expf(x0[j]), a0[j]);
            a1[j] = fmaf(ge, __expf(x1[j]), a1[j]);
        }
    }

    // reference: combined[combined==0] = float32(np.finfo(np.float64).eps)
    const float eps = 2.220446049250313e-16f;
    f32x4 r0, r1;
#pragma unroll
    for (int j = 0; j < 4; ++j) {
        const float c0 = (a0[j] == 0.f) ? eps : a0[j];
        const float c1 = (a1[j] == 0.f) ? eps : a1[j];
        r0[j] = __logf(c0);
        r1[j] = __logf(c1);
    }

    // non-temporal stores: don't evict L3-resident xs with the 25 MB output
    __builtin_nontemporal_store(r0, out4 + i0);
    __builtin_nontemporal_store(r1, out4 + i1);
}

extern "C" void kernel_launch(void* const* d_in, const int* in_sizes, int n_in,
                              void* d_out, int out_size, void* d_ws, size_t ws_size,
                              hipStream_t stream) {
    const float* xs    = (const float*)d_in[0];   // [E,B,L,D] fp32
    const float* gates = (const float*)d_in[1];   // [B,E] fp32
    float* out = (float*)d_out;                   // [B,L,D] fp32

    const int grid = NV4 / 512;   // 3072 blocks, 256 threads, 2 float4/thread
    moe_log_combine_kernel<<<grid, 256, 0, stream>>>(xs, gates, out);
}